// Round 12
// baseline (212.421 us; speedup 1.0000x reference)
//
#include <hip/hip_runtime.h>
#include <cstddef>

typedef _Float16 f16;
typedef _Float16 f16x8 __attribute__((ext_vector_type(8)));
typedef _Float16 f16x4 __attribute__((ext_vector_type(4)));
typedef _Float16 f16x2 __attribute__((ext_vector_type(2)));
typedef float f32x4 __attribute__((ext_vector_type(4)));
typedef float f32x16 __attribute__((ext_vector_type(16)));
typedef unsigned int u32;

__device__ inline float exp2_fast(float x) {
  float r;
  asm("v_exp_f32 %0, %1" : "=v"(r) : "v"(x));
  return r;
}

// pack two f32 -> f16x2 word (RTZ), as int for cross-lane ops
__device__ inline int pk2(float x, float y) {
  return __builtin_bit_cast(int, __builtin_amdgcn_cvt_pkrtz(x, y));
}

__device__ inline f16x2 pk2h(float x, float y) {
  return __builtin_bit_cast(f16x2, __builtin_amdgcn_cvt_pkrtz(x, y));
}

// v_permlane32_swap_b32: new_a[32:63] = old_b[0:31], new_b[0:31] = old_a[32:63]
__device__ inline void permlane32_swap(int& a, int& b) {
  asm volatile("v_permlane32_swap_b32 %0, %1" : "+v"(a), "+v"(b));
}

// global->LDS DMA, 16B per lane. LDS dest is wave-uniform base + lane*16;
// global src is per-lane (so swizzles are applied by permuting the SOURCE).
__device__ __forceinline__ void gload16(const f16* g, f16* l) {
  __builtin_amdgcn_global_load_lds(
      (const __attribute__((address_space(1))) void*)g,
      (__attribute__((address_space(3))) void*)l, 16, 0, 0);
}

// ---------------------------------------------------------------------------
// Prep, round 18: WEIGHTS ONLY (x-conversion deleted -- qkv_gemm now stages
// A from f32 directly, killing the 48 MB prep round-trip). Grid 4096.
// ---------------------------------------------------------------------------
__global__ __launch_bounds__(256) void prep(
    const float* __restrict__ Wq, const float* __restrict__ Wkv,
    const float* __restrict__ Wp, f16* __restrict__ Wqt,
    f16* __restrict__ Wkvt, f16* __restrict__ Wpt) {
  __shared__ float t[32][33];
  int zz = blockIdx.x;
  int bx = zz & 31, by = (zz >> 5) & 31, z = zz >> 10;
  const float* in;
  f16* out;
  int N = 1024, extra = 0;
  if (z == 0) { in = Wq; out = Wqt; }
  else if (z == 3) { in = Wp; out = Wpt; }
  else { in = Wkv; out = Wkvt; N = 2048; extra = (z - 1) * 1024; }
  int tx = threadIdx.x % 32, ty = threadIdx.x / 32;
  int n0 = bx * 32 + extra, k0 = by * 32;
#pragma unroll
  for (int i = 0; i < 32; i += 8)
    t[ty + i][tx] = in[(size_t)(k0 + ty + i) * N + n0 + tx];
  __syncthreads();
#pragma unroll
  for (int i = 0; i < 32; i += 8)
    out[(size_t)(n0 + ty + i) * 1024 + k0 + tx] = (f16)t[tx][ty + i];
}

// ---------------------------------------------------------------------------
// GEMM body, round 18: round-5 dbuf pipeline + round-10 epilogue (best
// measured: 201.1us). NEW: A may be f32 -- staged via regs with RTN casts
// into the SAME swizzled LDS slots the DMA path used (fragment reads
// unchanged; reg-staging proved perf-neutral in r4/r5). B always DMA from
// transposed f16 weights. T1 XCD-bijective tile swizzle.
// ---------------------------------------------------------------------------
template <int BN, typename CT, typename AT>
__device__ __forceinline__ void gemm_body(
    const AT* __restrict__ A, const f16* __restrict__ Bt, CT* __restrict__ C,
    int bid, int M, int N, int K, float scale, f16* As, f16* Bs) {
  constexpr int NT = BN / 32;
  constexpr int ASZ = 128 * 64;   // halfs per A buffer
  constexpr int BSZ = BN * 64;    // halfs per B buffer
  const int nb = N / BN;
  const int nwg = (M / 128) * nb;
  const int sbid = (bid & 7) * (nwg >> 3) + (bid >> 3);
  const int m0 = (sbid / nb) * 128;
  const int n0 = (sbid % nb) * BN;
  const int tid = threadIdx.x;
  const int w = tid >> 6, lane = tid & 63;
  const int l16 = lane & 15, quad = lane >> 4;
  const int wrow = (w >> 1) * 64, wcol = (w & 1) * (BN / 2);
  const int lrow = lane >> 3;
  const int lcs = (((lane & 7) ^ (lane >> 3)) & 7) * 8;

  f32x4 acc[4][NT] = {};

#define STAGE_TILE(bp, kk)                                                   \
  {                                                                          \
    if constexpr (sizeof(AT) == 4) {                                         \
      _Pragma("unroll") for (int i = 0; i < 4; i++) {                        \
        const int r = w * 32 + i * 8;                                        \
        const float* s_ = (const float*)&A[(size_t)(m0 + r + lrow) * K +     \
                                           (kk) + lcs];                      \
        float4 v0_ = *(const float4*)s_;                                     \
        float4 v1_ = *(const float4*)(s_ + 4);                               \
        f16x8 hh_;                                                           \
        hh_[0] = (f16)v0_.x; hh_[1] = (f16)v0_.y;                            \
        hh_[2] = (f16)v0_.z; hh_[3] = (f16)v0_.w;                            \
        hh_[4] = (f16)v1_.x; hh_[5] = (f16)v1_.y;                            \
        hh_[6] = (f16)v1_.z; hh_[7] = (f16)v1_.w;                            \
        *(f16x8*)&As[(bp) * ASZ + (r + lrow) * 64 + (lane & 7) * 8] = hh_;   \
      }                                                                      \
    } else {                                                                 \
      _Pragma("unroll") for (int i = 0; i < 4; i++) {                        \
        const int r = w * 32 + i * 8;                                        \
        gload16((const f16*)&A[(size_t)(m0 + r + lrow) * K + (kk) + lcs],    \
                &As[(bp) * ASZ + r * 64]);                                   \
      }                                                                      \
    }                                                                        \
    _Pragma("unroll") for (int i = 0; i < NT; i++) {                         \
      const int r = w * (BN / 4) + i * 8;                                    \
      gload16(&Bt[(size_t)(n0 + r + lrow) * K + (kk) + lcs],                 \
              &Bs[(bp) * BSZ + r * 64]);                                     \
    }                                                                        \
  }

  STAGE_TILE(0, 0);
  __syncthreads();  // tile 0 resident

  int buf = 0;
  for (int k0 = 0; k0 < K; k0 += 64) {
    if (k0 + 64 < K) STAGE_TILE(buf ^ 1, k0 + 64);

    const f16* Asb = &As[buf * ASZ];
    const f16* Bsb = &Bs[buf * BSZ];

    f16x8 bf[NT][2];
#pragma unroll
    for (int nt = 0; nt < NT; nt++) {
      const int row = wcol + nt * 16 + l16;
#pragma unroll
      for (int s = 0; s < 2; s++)
        bf[nt][s] = *(const f16x8*)&Bsb[row * 64 + (((s * 4 + quad) ^ (row & 7)) << 3)];
    }
#pragma unroll
    for (int mt = 0; mt < 4; mt++) {
      const int row = wrow + mt * 16 + l16;
      f16x8 af0 = *(const f16x8*)&Asb[row * 64 + ((quad ^ (row & 7)) << 3)];
      f16x8 af1 = *(const f16x8*)&Asb[row * 64 + (((4 + quad) ^ (row & 7)) << 3)];
#pragma unroll
      for (int nt = 0; nt < NT; nt++) {
        acc[mt][nt] = __builtin_amdgcn_mfma_f32_16x16x32_f16(af0, bf[nt][0], acc[mt][nt], 0, 0, 0);
        acc[mt][nt] = __builtin_amdgcn_mfma_f32_16x16x32_f16(af1, bf[nt][1], acc[mt][nt], 0, 0, 0);
      }
    }
    __syncthreads();
    buf ^= 1;
  }
#undef STAGE_TILE

  // round-10 epilogue (best measured)
#pragma unroll
  for (int mt = 0; mt < 4; mt++)
#pragma unroll
    for (int nt = 0; nt < NT; nt++)
#pragma unroll
      for (int r = 0; r < 4; r++) {
        int row = m0 + wrow + mt * 16 + quad * 4 + r;
        int col = n0 + wcol + nt * 16 + l16;
        C[(size_t)row * N + col] = (CT)(acc[mt][nt][r] * scale);
      }
}

// Fused Q + KV projection GEMMs, now consuming f32 x directly.
__global__ __launch_bounds__(256, 2) void qkv_gemm(
    const float* __restrict__ Xq, const f16* __restrict__ Wqt, f16* __restrict__ Qh,
    const float* __restrict__ Xkv, const f16* __restrict__ Wkvt, f16* __restrict__ KVh,
    float sc_q) {
  __shared__ f16 As[2 * 128 * 64];
  __shared__ f16 Bs[2 * 128 * 64];
  if (blockIdx.x < 256)
    gemm_body<128, f16, float>(Xq, Wqt, Qh, blockIdx.x, 4096, 1024, 1024, sc_q, As, Bs);
  else
    gemm_body<128, f16, float>(Xkv, Wkvt, KVh, blockIdx.x - 256, 4096, 2048, 1024, 1.0f, As, Bs);
}

// proj: BN=64, A = Yh f16 (DMA path), f32 output.
template <int BN, typename CT>
__global__ __launch_bounds__(256, 3) void gemm_lds(
    const f16* __restrict__ A, const f16* __restrict__ Bt, CT* __restrict__ C,
    int M, int N, int K, float scale) {
  __shared__ f16 As[2 * 128 * 64];
  __shared__ f16 Bs[2 * BN * 64];
  gemm_body<BN, CT, f16>(A, Bt, C, blockIdx.x, M, N, K, scale, As, Bs);
}

// ---------------------------------------------------------------------------
// Flash attention (EXACT round-5 version, FROZEN -- rounds 6/8 proved any
// added live state spills at VGPR=64): KV-split 2-way, 8 waves, in-register
// P via cvt_pkrtz+permlane32_swap, defer-max, cross-half merge. ~61 us.
// ---------------------------------------------------------------------------
__global__ __launch_bounds__(512, 4) void attn_kernel(
    const f16* __restrict__ Qh, const f16* __restrict__ KVh, f16* __restrict__ Yh) {
  __shared__ f16 smem[18432];  // 36864 B

  const int bid = blockIdx.x;
  const int hb = bid & 31;
  const int qt = bid >> 5;
  const int h = hb >> 1, b = hb & 1;
  const int tid = threadIdx.x;
  const int w = tid >> 6, lane = tid & 63;
  const int l31 = lane & 31, e = lane >> 5;
  const int qw = w & 3, half = w >> 2;
  const int tl = tid & 255;  // staging index within the half

  f16* Ks = smem + half * (2 * 64 * 72);  // this half's K tile [64 kv][72]
  f16* Vt = Ks + 64 * 72;                 // this half's V^T tile [64 d][72]

  const size_t qrow0 = (size_t)b * 2048 + (size_t)qt * 128;
  const size_t kvrow0 = (size_t)b * 2048 + (size_t)half * 1024;

  f16x8 qf[4];
#pragma unroll
  for (int ks = 0; ks < 4; ks++)
    qf[ks] = *(const f16x8*)&Qh[(qrow0 + qw * 32 + l31) * 1024 + h * 64 + ks * 16 + e * 8];

  float m_run = -1e30f, l_run = 0.0f;
  f32x16 o_acc[2] = {};

  const int ksr = tl >> 2, ksc = (tl & 3) << 4;
  const int vkv0 = (tl >> 3) * 2;
  const int vd0 = (tl & 7) * 8;
  const int vcol = ((((vkv0 >> 3) ^ (tl & 7)) << 3) | (vkv0 & 7));

  f16x8 kr0, kr1, vr0, vr1;
  {
    const f16* kb = &KVh[(kvrow0 + ksr) * 2048 + h * 64 + ksc];
    kr0 = *(const f16x8*)kb;
    kr1 = *(const f16x8*)(kb + 8);
    const f16* vb = &KVh[(kvrow0 + vkv0) * 2048 + 1024 + h * 64 + vd0];
    vr0 = *(const f16x8*)vb;
    vr1 = *(const f16x8*)(vb + 2048);
  }

  for (int t = 0; t < 16; t++) {
    *(f16x8*)&Ks[ksr * 72 + ksc] = kr0;
    *(f16x8*)&Ks[ksr * 72 + ksc + 8] = kr1;
#pragma unroll
    for (int j = 0; j < 8; j++) {
      f16x2 p; p[0] = vr0[j]; p[1] = vr1[j];
      *(f16x2*)&Vt[(vd0 + j) * 72 + vcol] = p;
    }
    __syncthreads();

    if (t + 1 < 16) {
      const f16* kb = &KVh[(kvrow0 + (t + 1) * 64 + ksr) * 2048 + h * 64 + ksc];
      kr0 = *(const f16x8*)kb;
      kr1 = *(const f16x8*)(kb + 8);
      const f16* vb = &KVh[(kvrow0 + (t + 1) * 64 + vkv0) * 2048 + 1024 + h * 64 + vd0];
      vr0 = *(const f16x8*)vb;
      vr1 = *(const f16x8*)(vb + 2048);
    }

    // ---- S = K @ Q^T : lane(q=l31,e) reg r holds kv=(r&3)+8*(r>>2)+4e ----
    f32x16 sacc[2] = {};
#pragma unroll
    for (int kvt = 0; kvt < 2; kvt++)
#pragma unroll
      for (int ks = 0; ks < 4; ks++) {
        f16x8 a = *(const f16x8*)&Ks[(kvt * 32 + l31) * 72 + ks * 16 + e * 8];
        sacc[kvt] = __builtin_amdgcn_mfma_f32_32x32x16_f16(a, qf[ks], sacc[kvt], 0, 0, 0);
      }

    // ---- tree max (max3-fusable, depth ~5) ----
    float mxa[4];
#pragma unroll
    for (int j = 0; j < 4; j++) {
      float a = fmaxf(fmaxf(sacc[0][j], sacc[0][j + 4]),
                      fmaxf(sacc[0][j + 8], sacc[0][j + 12]));
      float bb = fmaxf(fmaxf(sacc[1][j], sacc[1][j + 4]),
                       fmaxf(sacc[1][j + 8], sacc[1][j + 12]));
      mxa[j] = fmaxf(a, bb);
    }
    float mx = fmaxf(fmaxf(mxa[0], mxa[1]), fmaxf(mxa[2], mxa[3]));
    mx = fmaxf(mx, __shfl_xor(mx, 32, 64));

    // ---- defer-max: only rescale when the running max grew by > 8 ----
    if (!__all(mx <= m_run + 8.0f)) {
      float mnew = fmaxf(m_run, mx);
      float alpha = exp2_fast(m_run - mnew);
      m_run = mnew;
      l_run *= alpha;
#pragma unroll
      for (int r = 0; r < 16; r++) { o_acc[0][r] *= alpha; o_acc[1][r] *= alpha; }
    }

    // ---- P = exp2(S - m), 4-way split sum ----
    float ss0 = 0.0f, ss1 = 0.0f, ss2 = 0.0f, ss3 = 0.0f;
#pragma unroll
    for (int kvt = 0; kvt < 2; kvt++)
#pragma unroll
      for (int r = 0; r < 16; r += 4) {
        float p0 = exp2_fast(sacc[kvt][r + 0] - m_run);
        float p1 = exp2_fast(sacc[kvt][r + 1] - m_run);
        float p2 = exp2_fast(sacc[kvt][r + 2] - m_run);
        float p3 = exp2_fast(sacc[kvt][r + 3] - m_run);
        sacc[kvt][r + 0] = p0; sacc[kvt][r + 1] = p1;
        sacc[kvt][r + 2] = p2; sacc[kvt][r + 3] = p3;
        ss0 += p0; ss1 += p1; ss2 += p2; ss3 += p3;
      }
    float ssum = (ss0 + ss1) + (ss2 + ss3);
    ssum += __shfl_xor(ssum, 32, 64);
    l_run += ssum;

    // ---- P -> f16 B-fragments fully in-register (cvt_pkrtz + permlane32) ----
    f16x8 pf[4];
#pragma unroll
    for (int kvt = 0; kvt < 2; kvt++)
#pragma unroll
      for (int hf = 0; hf < 2; hf++) {
        const int h8 = hf * 8;
        int a0 = pk2(sacc[kvt][h8 + 0], sacc[kvt][h8 + 1]);
        int b0 = pk2(sacc[kvt][h8 + 4], sacc[kvt][h8 + 5]);
        int a1 = pk2(sacc[kvt][h8 + 2], sacc[kvt][h8 + 3]);
        int b1 = pk2(sacc[kvt][h8 + 6], sacc[kvt][h8 + 7]);
        permlane32_swap(a0, b0);   // a0 -> w0, b0 -> w2
        permlane32_swap(a1, b1);   // a1 -> w1, b1 -> w3
        union { int i[4]; f16x8 v; } u;
        u.i[0] = a0; u.i[1] = a1; u.i[2] = b0; u.i[3] = b1;
        pf[kvt * 2 + hf] = u.v;
      }

    // ---- O += V^T @ P ----
#pragma unroll
    for (int dt = 0; dt < 2; dt++) {
      const int d = dt * 32 + l31;
      const int dx = d >> 3;
#pragma unroll
      for (int ks = 0; ks < 4; ks++) {
        f16x8 va = *(const f16x8*)&Vt[d * 72 + (((ks * 2 + e) ^ dx) << 3)];
        o_acc[dt] = __builtin_amdgcn_mfma_f32_32x32x16_f16(va, pf[ks], o_acc[dt], 0, 0, 0);
      }
    }
    __syncthreads();
  }

  // ---- cross-half merge via LDS (one-time) ----
  float* Om = (float*)smem;
  float* ML = (float*)smem + 4 * 32 * 68;
  if (half == 1) {
#pragma unroll
    for (int dt = 0; dt < 2; dt++)
#pragma unroll
      for (int r2 = 0; r2 < 4; r2++) {
        f32x4 vv;
        vv[0] = o_acc[dt][r2 * 4 + 0];
        vv[1] = o_acc[dt][r2 * 4 + 1];
        vv[2] = o_acc[dt][r2 * 4 + 2];
        vv[3] = o_acc[dt][r2 * 4 + 3];
        *(f32x4*)&Om[(qw * 32 + l31) * 68 + dt * 32 + r2 * 8 + e * 4] = vv;
      }
    ML[qw * 64 + l31] = m_run;
    ML[qw * 64 + 32 + l31] = l_run;
  }
  __syncthreads();
  float linv = 0.0f;
  if (half == 0) {
    float m1 = ML[qw * 64 + l31], l1 = ML[qw * 64 + 32 + l31];
    float mm = fmaxf(m_run, m1);
    float a0 = exp2_fast(m_run - mm), a1 = exp2_fast(m1 - mm);
    linv = 1.0f / (l_run * a0 + l1 * a1);
#pragma unroll
    for (int dt = 0; dt < 2; dt++)
#pragma unroll
      for (int r2 = 0; r2 < 4; r2++) {
        f32x4 o1 = *(const f32x4*)&Om[(qw * 32 + l31) * 68 + dt * 32 + r2 * 8 + e * 4];
#pragma unroll
        for (int j = 0; j < 4; j++)
          o_acc[dt][r2 * 4 + j] = o_acc[dt][r2 * 4 + j] * a0 + o1[j] * a1;
      }
  }
  __syncthreads();

  // ---- epilogue (half 0 only): normalize, f16 reshuffle, coalesced write ----
  if (half == 0) {
    f16* Of = smem + qw * 32 * 72;  // [32 q][72] per-wave region
#pragma unroll
    for (int dt = 0; dt < 2; dt++)
#pragma unroll
      for (int r2 = 0; r2 < 4; r2++) {
        f16x2 h0 = pk2h(o_acc[dt][r2 * 4 + 0] * linv, o_acc[dt][r2 * 4 + 1] * linv);
        f16x2 h1 = pk2h(o_acc[dt][r2 * 4 + 2] * linv, o_acc[dt][r2 * 4 + 3] * linv);
        f16x4 hh; hh[0] = h0[0]; hh[1] = h0[1]; hh[2] = h1[0]; hh[3] = h1[1];
        *(f16x4*)&Of[l31 * 72 + dt * 32 + r2 * 8 + e * 4] = hh;
      }
    const int qq = lane >> 1, dh = (lane & 1) * 32;
#pragma unroll
    for (int j = 0; j < 4; j++) {
      f16x8 v = *(const f16x8*)&Of[qq * 72 + dh + j * 8];
      *(f16x8*)&Yh[(qrow0 + qw * 32 + qq) * 1024 + h * 64 + dh + j * 8] = v;
    }
  }
}

// ---------------------------------------------------------------------------
extern "C" void kernel_launch(void* const* d_in, const int* in_sizes, int n_in,
                              void* d_out, int out_size, void* d_ws, size_t ws_size,
                              hipStream_t stream) {
  const float* x_q  = (const float*)d_in[0];
  const float* x_kv = (const float*)d_in[1];
  const float* W_q  = (const float*)d_in[2];
  const float* W_kv = (const float*)d_in[3];
  const float* W_p  = (const float*)d_in[4];
  float* out = (float*)d_out;

  f16* Wq_t  = (f16*)d_ws;                       // [1024][1024]
  f16* Wkv_t = Wq_t  + (size_t)1024 * 1024;      // [2048][1024]
  f16* Wp_t  = Wkv_t + (size_t)2048 * 1024;      // [1024][1024]
  f16* Qh    = Wp_t  + (size_t)1024 * 1024;      // [4096][1024]
  f16* KVh   = Qh    + (size_t)4096 * 1024;      // [4096][2048]
  f16* Yh    = KVh   + (size_t)4096 * 2048;      // [4096][1024]

  prep<<<4096, 256, 0, stream>>>(W_q, W_kv, W_p, Wq_t, Wkv_t, Wp_t);

  const float SC = 11.5415603f;  // 8 * log2(e)
  qkv_gemm<<<768, 256, 0, stream>>>(x_q, Wq_t, Qh, x_kv, Wkv_t, KVh, SC);

  attn_kernel<<<512, 512, 0, stream>>>(Qh, KVh, Yh);

  gemm_lds<64, float><<<512, 256, 0, stream>>>(Yh, Wp_t, out, 4096, 1024, 1024, 1.0f);
}

// Round 13
// 197.619 us; speedup vs baseline: 1.0749x; 1.0749x over previous
//
#include <hip/hip_runtime.h>
#include <cstddef>

typedef _Float16 f16;
typedef _Float16 f16x8 __attribute__((ext_vector_type(8)));
typedef _Float16 f16x4 __attribute__((ext_vector_type(4)));
typedef _Float16 f16x2 __attribute__((ext_vector_type(2)));
typedef float f32x4 __attribute__((ext_vector_type(4)));
typedef float f32x16 __attribute__((ext_vector_type(16)));
typedef unsigned int u32;

__device__ inline float exp2_fast(float x) {
  float r;
  asm("v_exp_f32 %0, %1" : "=v"(r) : "v"(x));
  return r;
}

// pack two f32 -> f16x2 word (RTZ), as int for cross-lane ops
__device__ inline int pk2(float x, float y) {
  return __builtin_bit_cast(int, __builtin_amdgcn_cvt_pkrtz(x, y));
}

__device__ inline f16x2 pk2h(float x, float y) {
  return __builtin_bit_cast(f16x2, __builtin_amdgcn_cvt_pkrtz(x, y));
}

// v_permlane32_swap_b32: new_a[32:63] = old_b[0:31], new_b[0:31] = old_a[32:63]
__device__ inline void permlane32_swap(int& a, int& b) {
  asm volatile("v_permlane32_swap_b32 %0, %1" : "+v"(a), "+v"(b));
}

// global->LDS DMA, 16B per lane. LDS dest is wave-uniform base + lane*16;
// global src is per-lane (so swizzles are applied by permuting the SOURCE).
__device__ __forceinline__ void gload16(const f16* g, f16* l) {
  __builtin_amdgcn_global_load_lds(
      (const __attribute__((address_space(1))) void*)g,
      (__attribute__((address_space(3))) void*)l, 16, 0, 0);
}

// ---------------------------------------------------------------------------
// Fused prep (round-10 restore): blocks [0,4096) stream-convert x f32->f16
// at 8 elems/thread; blocks [4096,8192) transpose+convert weights.
// r12 counters proved in-GEMM f32-A staging costs ~11us vs this (+8us here).
// ---------------------------------------------------------------------------
__global__ __launch_bounds__(256) void prep(
    const float* __restrict__ xq, const float* __restrict__ xkv,
    f16* __restrict__ oq, f16* __restrict__ okv,
    const float* __restrict__ Wq, const float* __restrict__ Wkv,
    const float* __restrict__ Wp, f16* __restrict__ Wqt,
    f16* __restrict__ Wkvt, f16* __restrict__ Wpt) {
  __shared__ float t[32][33];
  int bid = blockIdx.x;
  if (bid < 4096) {
    const float* in = (bid < 2048) ? xq : xkv;
    f16* out = (bid < 2048) ? oq : okv;
    int i = (((bid & 2047) * 256 + threadIdx.x)) * 8;
    float4 v0 = *(const float4*)&in[i];
    float4 v1 = *(const float4*)&in[i + 4];
    f16x8 h;
    h[0] = (f16)v0.x; h[1] = (f16)v0.y; h[2] = (f16)v0.z; h[3] = (f16)v0.w;
    h[4] = (f16)v1.x; h[5] = (f16)v1.y; h[6] = (f16)v1.z; h[7] = (f16)v1.w;
    *(f16x8*)&out[i] = h;
  } else {
    int zz = bid - 4096;
    int bx = zz & 31, by = (zz >> 5) & 31, z = zz >> 10;
    const float* in;
    f16* out;
    int N = 1024, extra = 0;
    if (z == 0) { in = Wq; out = Wqt; }
    else if (z == 3) { in = Wp; out = Wpt; }
    else { in = Wkv; out = Wkvt; N = 2048; extra = (z - 1) * 1024; }
    int tx = threadIdx.x % 32, ty = threadIdx.x / 32;
    int n0 = bx * 32 + extra, k0 = by * 32;
#pragma unroll
    for (int i = 0; i < 32; i += 8)
      t[ty + i][tx] = in[(size_t)(k0 + ty + i) * N + n0 + tx];
    __syncthreads();
#pragma unroll
    for (int i = 0; i < 32; i += 8)
      out[(size_t)(n0 + ty + i) * 1024 + k0 + tx] = (f16)t[tx][ty + i];
  }
}

// ---------------------------------------------------------------------------
// GEMM body (round-5 dbuf pipeline + round-10 scalar epilogue, f16 A via
// DMA). r12 counters: latency-bound (MfmaUtil 15%, VALU 14%, HBM 16%,
// conflicts 0, occ 15%) -- so this round raises CONCURRENCY (qkv -> BN=64,
// 1536 blocks, 3 blocks/CU, zero scheduling tail) instead of rescheduling.
// ---------------------------------------------------------------------------
template <int BN, typename CT>
__device__ __forceinline__ void gemm_body(
    const f16* __restrict__ A, const f16* __restrict__ Bt, CT* __restrict__ C,
    int bid, int M, int N, int K, float scale, f16* As, f16* Bs) {
  constexpr int NT = BN / 32;
  constexpr int ASZ = 128 * 64;   // halfs per A buffer
  constexpr int BSZ = BN * 64;    // halfs per B buffer
  const int nb = N / BN;
  const int nwg = (M / 128) * nb;
  const int sbid = (bid & 7) * (nwg >> 3) + (bid >> 3);
  const int m0 = (sbid / nb) * 128;
  const int n0 = (sbid % nb) * BN;
  const int tid = threadIdx.x;
  const int w = tid >> 6, lane = tid & 63;
  const int l16 = lane & 15, quad = lane >> 4;
  const int wrow = (w >> 1) * 64, wcol = (w & 1) * (BN / 2);
  const int lrow = lane >> 3;
  const int lcs = (((lane & 7) ^ (lane >> 3)) & 7) * 8;

  f32x4 acc[4][NT] = {};

#define STAGE_TILE(bp, kk)                                                   \
  {                                                                          \
    _Pragma("unroll") for (int i = 0; i < 4; i++) {                          \
      const int r = w * 32 + i * 8;                                          \
      gload16(&A[(size_t)(m0 + r + lrow) * K + (kk) + lcs],                  \
              &As[(bp) * ASZ + r * 64]);                                     \
    }                                                                        \
    _Pragma("unroll") for (int i = 0; i < NT; i++) {                         \
      const int r = w * (BN / 4) + i * 8;                                    \
      gload16(&Bt[(size_t)(n0 + r + lrow) * K + (kk) + lcs],                 \
              &Bs[(bp) * BSZ + r * 64]);                                     \
    }                                                                        \
  }

  STAGE_TILE(0, 0);
  __syncthreads();  // tile 0 resident

  int buf = 0;
  for (int k0 = 0; k0 < K; k0 += 64) {
    if (k0 + 64 < K) STAGE_TILE(buf ^ 1, k0 + 64);

    const f16* Asb = &As[buf * ASZ];
    const f16* Bsb = &Bs[buf * BSZ];

    f16x8 bf[NT][2];
#pragma unroll
    for (int nt = 0; nt < NT; nt++) {
      const int row = wcol + nt * 16 + l16;
#pragma unroll
      for (int s = 0; s < 2; s++)
        bf[nt][s] = *(const f16x8*)&Bsb[row * 64 + (((s * 4 + quad) ^ (row & 7)) << 3)];
    }
#pragma unroll
    for (int mt = 0; mt < 4; mt++) {
      const int row = wrow + mt * 16 + l16;
      f16x8 af0 = *(const f16x8*)&Asb[row * 64 + ((quad ^ (row & 7)) << 3)];
      f16x8 af1 = *(const f16x8*)&Asb[row * 64 + (((4 + quad) ^ (row & 7)) << 3)];
#pragma unroll
      for (int nt = 0; nt < NT; nt++) {
        acc[mt][nt] = __builtin_amdgcn_mfma_f32_16x16x32_f16(af0, bf[nt][0], acc[mt][nt], 0, 0, 0);
        acc[mt][nt] = __builtin_amdgcn_mfma_f32_16x16x32_f16(af1, bf[nt][1], acc[mt][nt], 0, 0, 0);
      }
    }
    __syncthreads();
    buf ^= 1;
  }
#undef STAGE_TILE

  // round-10 scalar epilogue (best measured; r11's LDS variant was -4us)
#pragma unroll
  for (int mt = 0; mt < 4; mt++)
#pragma unroll
    for (int nt = 0; nt < NT; nt++)
#pragma unroll
      for (int r = 0; r < 4; r++) {
        int row = m0 + wrow + mt * 16 + quad * 4 + r;
        int col = n0 + wcol + nt * 16 + l16;
        C[(size_t)row * N + col] = (CT)(acc[mt][nt][r] * scale);
      }
}

// Fused Q + KV projection GEMMs, round 19: BN=64 for BOTH halves.
// Grid = Q 512 + KV 1024 = 1536 blocks; LDS 48KB -> 3 blocks/CU;
// 1536 = 2 exact generations of 768 resident blocks (zero tail),
// 12 waves/CU for latency interleave (r12: latency-bound, all pipes idle).
__global__ __launch_bounds__(256, 3) void qkv_gemm(
    const f16* __restrict__ Xq, const f16* __restrict__ Wqt, f16* __restrict__ Qh,
    const f16* __restrict__ Xkv, const f16* __restrict__ Wkvt, f16* __restrict__ KVh,
    float sc_q) {
  __shared__ f16 As[2 * 128 * 64];
  __shared__ f16 Bs[2 * 64 * 64];
  if (blockIdx.x < 512)
    gemm_body<64, f16>(Xq, Wqt, Qh, blockIdx.x, 4096, 1024, 1024, sc_q, As, Bs);
  else
    gemm_body<64, f16>(Xkv, Wkvt, KVh, blockIdx.x - 512, 4096, 2048, 1024, 1.0f, As, Bs);
}

// proj: BN=64, dbuf LDS = 48 KB -> 3 blocks/CU (unchanged).
template <int BN, typename CT>
__global__ __launch_bounds__(256, 3) void gemm_lds(
    const f16* __restrict__ A, const f16* __restrict__ Bt, CT* __restrict__ C,
    int M, int N, int K, float scale) {
  __shared__ f16 As[2 * 128 * 64];
  __shared__ f16 Bs[2 * BN * 64];
  gemm_body<BN, CT>(A, Bt, C, blockIdx.x, M, N, K, scale, As, Bs);
}

// ---------------------------------------------------------------------------
// Flash attention (EXACT round-5 version, FROZEN): KV-split 2-way, 8 waves,
// in-register P via cvt_pkrtz+permlane32_swap, defer-max, cross-half merge.
// ---------------------------------------------------------------------------
__global__ __launch_bounds__(512, 4) void attn_kernel(
    const f16* __restrict__ Qh, const f16* __restrict__ KVh, f16* __restrict__ Yh) {
  __shared__ f16 smem[18432];  // 36864 B

  const int bid = blockIdx.x;
  const int hb = bid & 31;
  const int qt = bid >> 5;
  const int h = hb >> 1, b = hb & 1;
  const int tid = threadIdx.x;
  const int w = tid >> 6, lane = tid & 63;
  const int l31 = lane & 31, e = lane >> 5;
  const int qw = w & 3, half = w >> 2;
  const int tl = tid & 255;  // staging index within the half

  f16* Ks = smem + half * (2 * 64 * 72);  // this half's K tile [64 kv][72]
  f16* Vt = Ks + 64 * 72;                 // this half's V^T tile [64 d][72]

  const size_t qrow0 = (size_t)b * 2048 + (size_t)qt * 128;
  const size_t kvrow0 = (size_t)b * 2048 + (size_t)half * 1024;

  f16x8 qf[4];
#pragma unroll
  for (int ks = 0; ks < 4; ks++)
    qf[ks] = *(const f16x8*)&Qh[(qrow0 + qw * 32 + l31) * 1024 + h * 64 + ks * 16 + e * 8];

  float m_run = -1e30f, l_run = 0.0f;
  f32x16 o_acc[2] = {};

  const int ksr = tl >> 2, ksc = (tl & 3) << 4;
  const int vkv0 = (tl >> 3) * 2;
  const int vd0 = (tl & 7) * 8;
  const int vcol = ((((vkv0 >> 3) ^ (tl & 7)) << 3) | (vkv0 & 7));

  f16x8 kr0, kr1, vr0, vr1;
  {
    const f16* kb = &KVh[(kvrow0 + ksr) * 2048 + h * 64 + ksc];
    kr0 = *(const f16x8*)kb;
    kr1 = *(const f16x8*)(kb + 8);
    const f16* vb = &KVh[(kvrow0 + vkv0) * 2048 + 1024 + h * 64 + vd0];
    vr0 = *(const f16x8*)vb;
    vr1 = *(const f16x8*)(vb + 2048);
  }

  for (int t = 0; t < 16; t++) {
    *(f16x8*)&Ks[ksr * 72 + ksc] = kr0;
    *(f16x8*)&Ks[ksr * 72 + ksc + 8] = kr1;
#pragma unroll
    for (int j = 0; j < 8; j++) {
      f16x2 p; p[0] = vr0[j]; p[1] = vr1[j];
      *(f16x2*)&Vt[(vd0 + j) * 72 + vcol] = p;
    }
    __syncthreads();

    if (t + 1 < 16) {
      const f16* kb = &KVh[(kvrow0 + (t + 1) * 64 + ksr) * 2048 + h * 64 + ksc];
      kr0 = *(const f16x8*)kb;
      kr1 = *(const f16x8*)(kb + 8);
      const f16* vb = &KVh[(kvrow0 + (t + 1) * 64 + vkv0) * 2048 + 1024 + h * 64 + vd0];
      vr0 = *(const f16x8*)vb;
      vr1 = *(const f16x8*)(vb + 2048);
    }

    // ---- S = K @ Q^T : lane(q=l31,e) reg r holds kv=(r&3)+8*(r>>2)+4e ----
    f32x16 sacc[2] = {};
#pragma unroll
    for (int kvt = 0; kvt < 2; kvt++)
#pragma unroll
      for (int ks = 0; ks < 4; ks++) {
        f16x8 a = *(const f16x8*)&Ks[(kvt * 32 + l31) * 72 + ks * 16 + e * 8];
        sacc[kvt] = __builtin_amdgcn_mfma_f32_32x32x16_f16(a, qf[ks], sacc[kvt], 0, 0, 0);
      }

    // ---- tree max (max3-fusable, depth ~5) ----
    float mxa[4];
#pragma unroll
    for (int j = 0; j < 4; j++) {
      float a = fmaxf(fmaxf(sacc[0][j], sacc[0][j + 4]),
                      fmaxf(sacc[0][j + 8], sacc[0][j + 12]));
      float bb = fmaxf(fmaxf(sacc[1][j], sacc[1][j + 4]),
                       fmaxf(sacc[1][j + 8], sacc[1][j + 12]));
      mxa[j] = fmaxf(a, bb);
    }
    float mx = fmaxf(fmaxf(mxa[0], mxa[1]), fmaxf(mxa[2], mxa[3]));
    mx = fmaxf(mx, __shfl_xor(mx, 32, 64));

    // ---- defer-max: only rescale when the running max grew by > 8 ----
    if (!__all(mx <= m_run + 8.0f)) {
      float mnew = fmaxf(m_run, mx);
      float alpha = exp2_fast(m_run - mnew);
      m_run = mnew;
      l_run *= alpha;
#pragma unroll
      for (int r = 0; r < 16; r++) { o_acc[0][r] *= alpha; o_acc[1][r] *= alpha; }
    }

    // ---- P = exp2(S - m), 4-way split sum ----
    float ss0 = 0.0f, ss1 = 0.0f, ss2 = 0.0f, ss3 = 0.0f;
#pragma unroll
    for (int kvt = 0; kvt < 2; kvt++)
#pragma unroll
      for (int r = 0; r < 16; r += 4) {
        float p0 = exp2_fast(sacc[kvt][r + 0] - m_run);
        float p1 = exp2_fast(sacc[kvt][r + 1] - m_run);
        float p2 = exp2_fast(sacc[kvt][r + 2] - m_run);
        float p3 = exp2_fast(sacc[kvt][r + 3] - m_run);
        sacc[kvt][r + 0] = p0; sacc[kvt][r + 1] = p1;
        sacc[kvt][r + 2] = p2; sacc[kvt][r + 3] = p3;
        ss0 += p0; ss1 += p1; ss2 += p2; ss3 += p3;
      }
    float ssum = (ss0 + ss1) + (ss2 + ss3);
    ssum += __shfl_xor(ssum, 32, 64);
    l_run += ssum;

    // ---- P -> f16 B-fragments fully in-register (cvt_pkrtz + permlane32) ----
    f16x8 pf[4];
#pragma unroll
    for (int kvt = 0; kvt < 2; kvt++)
#pragma unroll
      for (int hf = 0; hf < 2; hf++) {
        const int h8 = hf * 8;
        int a0 = pk2(sacc[kvt][h8 + 0], sacc[kvt][h8 + 1]);
        int b0 = pk2(sacc[kvt][h8 + 4], sacc[kvt][h8 + 5]);
        int a1 = pk2(sacc[kvt][h8 + 2], sacc[kvt][h8 + 3]);
        int b1 = pk2(sacc[kvt][h8 + 6], sacc[kvt][h8 + 7]);
        permlane32_swap(a0, b0);   // a0 -> w0, b0 -> w2
        permlane32_swap(a1, b1);   // a1 -> w1, b1 -> w3
        union { int i[4]; f16x8 v; } u;
        u.i[0] = a0; u.i[1] = a1; u.i[2] = b0; u.i[3] = b1;
        pf[kvt * 2 + hf] = u.v;
      }

    // ---- O += V^T @ P ----
#pragma unroll
    for (int dt = 0; dt < 2; dt++) {
      const int d = dt * 32 + l31;
      const int dx = d >> 3;
#pragma unroll
      for (int ks = 0; ks < 4; ks++) {
        f16x8 va = *(const f16x8*)&Vt[d * 72 + (((ks * 2 + e) ^ dx) << 3)];
        o_acc[dt] = __builtin_amdgcn_mfma_f32_32x32x16_f16(va, pf[ks], o_acc[dt], 0, 0, 0);
      }
    }
    __syncthreads();
  }

  // ---- cross-half merge via LDS (one-time) ----
  float* Om = (float*)smem;
  float* ML = (float*)smem + 4 * 32 * 68;
  if (half == 1) {
#pragma unroll
    for (int dt = 0; dt < 2; dt++)
#pragma unroll
      for (int r2 = 0; r2 < 4; r2++) {
        f32x4 vv;
        vv[0] = o_acc[dt][r2 * 4 + 0];
        vv[1] = o_acc[dt][r2 * 4 + 1];
        vv[2] = o_acc[dt][r2 * 4 + 2];
        vv[3] = o_acc[dt][r2 * 4 + 3];
        *(f32x4*)&Om[(qw * 32 + l31) * 68 + dt * 32 + r2 * 8 + e * 4] = vv;
      }
    ML[qw * 64 + l31] = m_run;
    ML[qw * 64 + 32 + l31] = l_run;
  }
  __syncthreads();
  float linv = 0.0f;
  if (half == 0) {
    float m1 = ML[qw * 64 + l31], l1 = ML[qw * 64 + 32 + l31];
    float mm = fmaxf(m_run, m1);
    float a0 = exp2_fast(m_run - mm), a1 = exp2_fast(m1 - mm);
    linv = 1.0f / (l_run * a0 + l1 * a1);
#pragma unroll
    for (int dt = 0; dt < 2; dt++)
#pragma unroll
      for (int r2 = 0; r2 < 4; r2++) {
        f32x4 o1 = *(const f32x4*)&Om[(qw * 32 + l31) * 68 + dt * 32 + r2 * 8 + e * 4];
#pragma unroll
        for (int j = 0; j < 4; j++)
          o_acc[dt][r2 * 4 + j] = o_acc[dt][r2 * 4 + j] * a0 + o1[j] * a1;
      }
  }
  __syncthreads();

  // ---- epilogue (half 0 only): normalize, f16 reshuffle, coalesced write ----
  if (half == 0) {
    f16* Of = smem + qw * 32 * 72;  // [32 q][72] per-wave region
#pragma unroll
    for (int dt = 0; dt < 2; dt++)
#pragma unroll
      for (int r2 = 0; r2 < 4; r2++) {
        f16x2 h0 = pk2h(o_acc[dt][r2 * 4 + 0] * linv, o_acc[dt][r2 * 4 + 1] * linv);
        f16x2 h1 = pk2h(o_acc[dt][r2 * 4 + 2] * linv, o_acc[dt][r2 * 4 + 3] * linv);
        f16x4 hh; hh[0] = h0[0]; hh[1] = h0[1]; hh[2] = h1[0]; hh[3] = h1[1];
        *(f16x4*)&Of[l31 * 72 + dt * 32 + r2 * 8 + e * 4] = hh;
      }
    const int qq = lane >> 1, dh = (lane & 1) * 32;
#pragma unroll
    for (int j = 0; j < 4; j++) {
      f16x8 v = *(const f16x8*)&Of[qq * 72 + dh + j * 8];
      *(f16x8*)&Yh[(qrow0 + qw * 32 + qq) * 1024 + h * 64 + dh + j * 8] = v;
    }
  }
}

// ---------------------------------------------------------------------------
extern "C" void kernel_launch(void* const* d_in, const int* in_sizes, int n_in,
                              void* d_out, int out_size, void* d_ws, size_t ws_size,
                              hipStream_t stream) {
  const float* x_q  = (const float*)d_in[0];
  const float* x_kv = (const float*)d_in[1];
  const float* W_q  = (const float*)d_in[2];
  const float* W_kv = (const float*)d_in[3];
  const float* W_p  = (const float*)d_in[4];
  float* out = (float*)d_out;

  f16* Wq_t  = (f16*)d_ws;                       // [1024][1024]
  f16* Wkv_t = Wq_t  + (size_t)1024 * 1024;      // [2048][1024]
  f16* Wp_t  = Wkv_t + (size_t)2048 * 1024;      // [1024][1024]
  f16* Qh    = Wp_t  + (size_t)1024 * 1024;      // [4096][1024]
  f16* KVh   = Qh    + (size_t)4096 * 1024;      // [4096][2048]
  f16* Yh    = KVh   + (size_t)4096 * 2048;      // [4096][1024]
  f16* Xq_h  = Yh;                               // alias (dead after qkv_gemm)
  f16* Xkv_h = Yh    + (size_t)4096 * 1024;      // [4096][1024]

  prep<<<8192, 256, 0, stream>>>(x_q, x_kv, Xq_h, Xkv_h,
                                 W_q, W_kv, W_p, Wq_t, Wkv_t, Wp_t);

  const float SC = 11.5415603f;  // 8 * log2(e)
  qkv_gemm<<<1536, 256, 0, stream>>>(Xq_h, Wq_t, Qh, Xkv_h, Wkv_t, KVh, SC);

  attn_kernel<<<512, 512, 0, stream>>>(Qh, KVh, Yh);

  gemm_lds<64, float><<<512, 256, 0, stream>>>(Yh, Wp_t, out, 4096, 1024, 1024, 1.0f);
}